// Round 15
// baseline (324.540 us; speedup 1.0000x reference)
//
#include <hip/hip_runtime.h>
#include <math.h>

#define NB 128          // batch of graphs
#define E_PER 2048
#define NE (NB * E_PER) // 262144 edges
#define FD 128          // feature dim (F_IN = NHID)

// ------- GEMM 32x128 tile / 256 thr, K chunks of 32. LDS ~21KB ----------------
// Register-prefetch double-buffer: chunk k+1's global loads issue before chunk
// k's compute, hiding global latency under FMAs (barriers unchanged).
// XCD swizzle: graph(tile) -> XCD (g&7). If bid >= ngemm: run stage-1 CSR build.
__global__ __launch_bounds__(256) void gemm32(const float* __restrict__ A,
                                              const float* __restrict__ W,
                                              float* __restrict__ C,
                                              int swz_shift, int ngemm,
                                              const int* __restrict__ src0,
                                              const int* __restrict__ dst0,
                                              float* __restrict__ dinv,
                                              int* __restrict__ roff,
                                              float2* __restrict__ cpair) {
    __shared__ float smem[5248];           // gemm: At[1152]+Wt[4096]; build: reuse
    const int tid = threadIdx.x;
    const int bid = blockIdx.x;

    if (bid >= ngemm) {
        // ---------- stage-1 CSR build (identity map), one block per graph ------
        int* cnt  = (int*)&smem[0];        // [512]
        int* offs = (int*)&smem[512];      // [513]
        float* dl = &smem[1025];           // [512]
        const int g = bid - ngemm;
        const int ebase = g * E_PER;
        const int nbase = g * 512;
        for (int i = tid; i < 512; i += 256) cnt[i] = 0;
        __syncthreads();
        for (int i = tid; i < E_PER; i += 256)
            atomicAdd(&cnt[dst0[ebase + i] - nbase], 1);
        __syncthreads();
        for (int i = tid; i < 512; i += 256) {
            float di = rsqrtf(1.0f + (float)cnt[i]);
            dl[i] = di;
            dinv[nbase + i] = di;
        }
        __syncthreads();
        if (tid == 0) {
            int run = 0;
            for (int i = 0; i < 512; ++i) { offs[i] = run; run += cnt[i]; }
            offs[512] = run;
        }
        __syncthreads();
        for (int i = tid; i <= 512; i += 256) roff[g * 513 + i] = ebase + offs[i];
        for (int i = tid; i < 512; i += 256) cnt[i] = offs[i];
        __syncthreads();
        for (int i = tid; i < E_PER; i += 256) {
            int s = src0[ebase + i] - nbase, d = dst0[ebase + i] - nbase;
            int pos = atomicAdd(&cnt[d], 1);
            cpair[ebase + pos] = make_float2(__int_as_float(nbase + s), dl[s] * dl[d]);
        }
        return;
    }

    // ---------- gemm body ----------
    float* At = &smem[0];      // [32k][36row] transposed, pad 36
    float* Wt = &smem[1152];   // [32k][128col]
    const int xcd = bid & 7;
    const int q = bid >> 3;
    const int S = swz_shift;
    const int tile = ((q >> S) << (3 + S)) | (xcd << S) | (q & ((1 << S) - 1));
    const long rbase = (long)tile * 32;
    const int cq = tid & 31, rg = tid >> 5;   // 32 col-quads x 8 row-quads
    const int arow = tid >> 3, akq = tid & 7; // A staging coords (8 rows x 128B)

    float acc[4][4];
#pragma unroll
    for (int i = 0; i < 4; ++i)
#pragma unroll
        for (int j = 0; j < 4; ++j) acc[i][j] = 0.f;

    // prologue: prefetch chunk 0 into registers
    float4 aReg = *(const float4*)&A[(rbase + arow) * FD + akq * 4];
    float4 wReg[4];
#pragma unroll
    for (int qq = 0; qq < 4; ++qq) {
        int idx = tid + 256 * qq;
        int kk = idx >> 5, c4 = idx & 31;
        wReg[qq] = *(const float4*)&W[kk * FD + c4 * 4];
    }

    for (int k0 = 0; k0 < 128; k0 += 32) {
        __syncthreads();                      // prev compute done reading LDS
        At[(akq * 4 + 0) * 36 + arow] = aReg.x;
        At[(akq * 4 + 1) * 36 + arow] = aReg.y;
        At[(akq * 4 + 2) * 36 + arow] = aReg.z;
        At[(akq * 4 + 3) * 36 + arow] = aReg.w;
#pragma unroll
        for (int qq = 0; qq < 4; ++qq) {
            int idx = tid + 256 * qq;
            int kk = idx >> 5, c4 = idx & 31;
            *(float4*)&Wt[kk * 128 + c4 * 4] = wReg[qq];
        }
        __syncthreads();
        if (k0 < 96) {                        // prefetch next chunk (in-flight
            aReg = *(const float4*)&A[(rbase + arow) * FD + (k0 + 32) + akq * 4];
#pragma unroll
            for (int qq = 0; qq < 4; ++qq) {  //  during compute below)
                int idx = tid + 256 * qq;
                int kk = idx >> 5, c4 = idx & 31;
                wReg[qq] = *(const float4*)&W[(k0 + 32 + kk) * FD + c4 * 4];
            }
        }
#pragma unroll 4
        for (int kk = 0; kk < 32; ++kk) {
            float4 a = *(const float4*)&At[kk * 36 + rg * 4];   // bcast per half-wave
            float4 b = *(const float4*)&Wt[kk * 128 + cq * 4];  // 32 seq quads
            float av[4] = {a.x, a.y, a.z, a.w};
            float bv[4] = {b.x, b.y, b.z, b.w};
#pragma unroll
            for (int i = 0; i < 4; ++i)
#pragma unroll
                for (int j = 0; j < 4; ++j) acc[i][j] += av[i] * bv[j];
        }
    }
#pragma unroll
    for (int i = 0; i < 4; ++i) {
        float4 o = {acc[i][0], acc[i][1], acc[i][2], acc[i][3]};
        *(float4*)&C[(rbase + rg * 4 + i) * FD + cq * 4] = o;
    }
}

// -------- aggregate via CSR gather + FUSED raw pool-score ---------------------
// ONE WAVE per node: 64 lanes x float2. 4 nodes/block. XCD-pinned (g&7).
__global__ __launch_bounds__(256) void agg_csr(const float* __restrict__ hpre,
                                               const int* __restrict__ roff,
                                               const float2* __restrict__ cpair,
                                               const float* __restrict__ dinv,
                                               const float* __restrict__ bias,
                                               const float* __restrict__ pvec,
                                               int np_shift,
                                               float* __restrict__ hout,
                                               float* __restrict__ scraw) {
    const int tid = threadIdx.x;
    const int P = 1 << (np_shift - 2);
    const int xcd = blockIdx.x & 7;
    const int idx = blockIdx.x >> 3;
    const int p = idx & (P - 1);
    const int g = ((idx >> (np_shift - 2)) << 3) + xcd;
    const int n_per = 1 << np_shift;
    const int nl = p * 4 + (tid >> 6);
    const int node = g * n_per + nl;
    const int l = tid & 63;
    const float2* __restrict__ hpre2 = (const float2*)hpre;
    const int rbase = g * (n_per + 1) + nl;
    const int e0 = roff[rbase], e1 = roff[rbase + 1];
    const float2 selfh = hpre2[(long)node * 64 + l];
    float ax = 0.f, ay = 0.f;
    int e = e0, n = e1 - e0;
    while (n >= 4) {
        float2 p0 = cpair[e], p1 = cpair[e + 1], p2 = cpair[e + 2], p3 = cpair[e + 3];
        float2 h0 = hpre2[(long)__float_as_int(p0.x) * 64 + l];
        float2 h1 = hpre2[(long)__float_as_int(p1.x) * 64 + l];
        float2 h2 = hpre2[(long)__float_as_int(p2.x) * 64 + l];
        float2 h3 = hpre2[(long)__float_as_int(p3.x) * 64 + l];
        ax += h0.x * p0.y + h1.x * p1.y + h2.x * p2.y + h3.x * p3.y;
        ay += h0.y * p0.y + h1.y * p1.y + h2.y * p2.y + h3.y * p3.y;
        e += 4; n -= 4;
    }
    while (n > 0) {
        float2 pr = cpair[e];
        float2 hv = hpre2[(long)__float_as_int(pr.x) * 64 + l];
        ax += hv.x * pr.y;
        ay += hv.y * pr.y;
        ++e; --n;
    }
    const float di = dinv[node];
    const float d2 = di * di;
    const float2 bb = ((const float2*)bias)[l];
    float v0 = fmaxf(ax + selfh.x * d2 + bb.x, 0.f);
    float v1 = fmaxf(ay + selfh.y * d2 + bb.y, 0.f);
    ((float2*)hout)[(long)node * 64 + l] = make_float2(v0, v1);

    const float2 pv = ((const float2*)pvec)[l];
    float pr = v0 * pv.x + v1 * pv.y;
#pragma unroll
    for (int o = 32; o > 0; o >>= 1) pr += __shfl_down(pr, o);
    if (l == 0) scraw[node] = pr;
}

// ---- TopK pool (rank-select) + readout, FUSED next-stage CSR build / MLP -----
template<int STAGE>
__global__ __launch_bounds__(1024) void pool_fused(
    const float* __restrict__ h, const float* __restrict__ scraw,
    const float* __restrict__ p,
    float* __restrict__ xp, int* __restrict__ nid1, float* __restrict__ rout,
    const int* __restrict__ src0, const int* __restrict__ dst0,
    float* __restrict__ dinv, int* __restrict__ roff, float2* __restrict__ cpair,
    const float* __restrict__ r1, const float* __restrict__ r2,
    const float* __restrict__ L1, const float* __restrict__ bl1,
    const float* __restrict__ L2, const float* __restrict__ bl2,
    const float* __restrict__ L3, const float* __restrict__ bl3,
    float* __restrict__ out) {
    constexpr int n_per = (STAGE == 1) ? 512 : (STAGE == 2) ? 256 : 128;
    constexpr int k = n_per / 2;
    constexpr int n_next = k;
    __shared__ float sc[512];
    __shared__ int   ord[256];
    __shared__ float tf[256];
    __shared__ float red[128];
    __shared__ float mxs[1024];
    __shared__ float sms[1024];
    __shared__ int   nidl[512];    // current-stage node -> local rank (or -1)
    __shared__ int   cnt[256];
    __shared__ int   offs[257];
    __shared__ float dl2[256];
    __shared__ int   nid1l[512];   // STAGE==2: orig node -> stage-2 local id
    __shared__ float z[256], z1[128], z2[64];

    const int tid = threadIdx.x;
    const int g = blockIdx.x;
    const int nbase = g * n_per;

    if (tid < 128) { float pv = p[tid]; red[tid] = pv * pv; }
    __syncthreads();
    for (int s = 64; s > 0; s >>= 1) {
        if (tid < s) red[tid] += red[tid + s];
        __syncthreads();
    }
    const float invn = rsqrtf(red[0]);

    if (tid < n_per) sc[tid] = scraw[nbase + tid] * invn;
    __syncthreads();

    if (tid < n_per) {
        const float si = sc[tid];
        int rank = 0;
        for (int j = 0; j < n_per; ++j) {
            float sj = sc[j];
            rank += (sj > si) || (sj == si && j < tid);
        }
        if (rank < k) { ord[rank] = tid; tf[rank] = tanhf(si); nidl[tid] = rank; }
        else nidl[tid] = -1;
        if (STAGE == 1) nid1[nbase + tid] = (nidl[tid] < 0) ? -1 : g * k + nidl[tid];
    }
    __syncthreads();

    // gather + [max || mean] readout; f fixed per thread
    const int f = tid & 127;
    const int grp = tid >> 7;    // 0..7
    float mx = -INFINITY, sm = 0.f;
    for (int t = tid; t < k * FD; t += 1024) {
        int r = t >> 7;
        float val = h[(long)(nbase + ord[r]) * FD + f] * tf[r];
        if (STAGE < 3) xp[((long)g * k + r) * FD + f] = val;
        mx = fmaxf(mx, val);
        sm += val;
    }
    mxs[grp * 128 + f] = mx;
    sms[grp * 128 + f] = sm;
    __syncthreads();
    float m0 = 0.f, s0 = 0.f;
    if (tid < 128) {
        m0 = mxs[f]; s0 = sms[f];
#pragma unroll
        for (int qq = 1; qq < 8; ++qq) {
            m0 = fmaxf(m0, mxs[qq * 128 + f]);
            s0 += sms[qq * 128 + f];
        }
        if (STAGE < 3) {
            rout[g * 256 + f] = m0;
            rout[g * 256 + 128 + f] = s0 / (float)k;
        }
    }

    if constexpr (STAGE < 3) {
        // ---------- build next-stage CSR (all per-graph local) ----------
        if (STAGE == 2) {
            for (int i = tid; i < 512; i += 1024) {
                int v = nid1[g * 512 + i];
                nid1l[i] = (v < 0) ? -1 : (v - g * 256);
            }
        }
        for (int i = tid; i < n_next; i += 1024) cnt[i] = 0;
        __syncthreads();
        const int ebase = g * E_PER;
        auto edge_map = [&](int orig) -> int {
            int v = orig - g * 512;            // src0/dst0 hold original ids
            if (STAGE == 1) return nidl[v];
            int m = nid1l[v];
            return (m < 0) ? -1 : nidl[m];
        };
        for (int i = tid; i < E_PER; i += 1024) {
            int ms = edge_map(src0[ebase + i]);
            int md = edge_map(dst0[ebase + i]);
            if (ms >= 0 && md >= 0) atomicAdd(&cnt[md], 1);
        }
        __syncthreads();
        for (int i = tid; i < n_next; i += 1024) {
            float di = rsqrtf(1.0f + (float)cnt[i]);
            dl2[i] = di;
            dinv[g * n_next + i] = di;
        }
        __syncthreads();
        if (tid == 0) {
            int run = 0;
            for (int i = 0; i < n_next; ++i) { offs[i] = run; run += cnt[i]; }
            offs[n_next] = run;
        }
        __syncthreads();
        for (int i = tid; i <= n_next; i += 1024)
            roff[g * (n_next + 1) + i] = ebase + offs[i];
        for (int i = tid; i < n_next; i += 1024) cnt[i] = offs[i];
        __syncthreads();
        for (int i = tid; i < E_PER; i += 1024) {
            int ms = edge_map(src0[ebase + i]);
            int md = edge_map(dst0[ebase + i]);
            if (ms >= 0 && md >= 0) {
                int pos = atomicAdd(&cnt[md], 1);
                cpair[ebase + pos] =
                    make_float2(__int_as_float(g * n_next + ms), dl2[ms] * dl2[md]);
            }
        }
    } else {
        // ---------- fused final MLP + log_softmax ----------
        if (tid < 128) {
            z[f]       = r1[g * 256 + f]       + r2[g * 256 + f]       + m0;
            z[128 + f] = r1[g * 256 + 128 + f] + r2[g * 256 + 128 + f] + s0 / (float)k;
        }
        __syncthreads();
        if (tid < 128) {
            float a = bl1[tid];
            for (int i = 0; i < 256; ++i) a += z[i] * L1[i * 128 + tid];
            z1[tid] = fmaxf(a, 0.f);
        }
        __syncthreads();
        if (tid < 64) {
            float a = bl2[tid];
            for (int i = 0; i < 128; ++i) a += z1[i] * L2[i * 64 + tid];
            z2[tid] = fmaxf(a, 0.f);
        }
        __syncthreads();
        if (tid == 0) {
            float l0 = bl3[0], l1v = bl3[1];
            for (int i = 0; i < 64; ++i) {
                l0  += z2[i] * L3[i * 2 + 0];
                l1v += z2[i] * L3[i * 2 + 1];
            }
            float m = fmaxf(l0, l1v);
            float lse = m + logf(expf(l0 - m) + expf(l1v - m));
            out[g * 2 + 0] = l0 - lse;
            out[g * 2 + 1] = l1v - lse;
        }
    }
}

extern "C" void kernel_launch(void* const* d_in, const int* in_sizes, int n_in,
                              void* d_out, int out_size, void* d_ws, size_t ws_size,
                              hipStream_t stream) {
    const float* x   = (const float*)d_in[0];
    const int*  src0 = (const int*)d_in[1];
    const int*  dst0 = (const int*)d_in[2];
    const float* W1 = (const float*)d_in[3];  const float* b1  = (const float*)d_in[4];
    const float* W2 = (const float*)d_in[5];  const float* b2  = (const float*)d_in[6];
    const float* W3 = (const float*)d_in[7];  const float* b3  = (const float*)d_in[8];
    const float* p1 = (const float*)d_in[9];  const float* p2  = (const float*)d_in[10];
    const float* p3 = (const float*)d_in[11];
    const float* L1 = (const float*)d_in[12]; const float* bl1 = (const float*)d_in[13];
    const float* L2 = (const float*)d_in[14]; const float* bl2 = (const float*)d_in[15];
    const float* L3 = (const float*)d_in[16]; const float* bl3 = (const float*)d_in[17];
    float* out = (float*)d_out;

    char* wptr = (char*)d_ws;
    auto alloc = [&](size_t bytes) {
        char* r = wptr;
        wptr += (bytes + 255) & ~(size_t)255;
        return r;
    };
    float* hpre = (float*)alloc(65536ULL * FD * 4);
    float* hbuf = (float*)alloc(65536ULL * FD * 4);
    float* xp2  = (float*)alloc(32768ULL * FD * 4);
    float* xp3  = (float*)alloc(16384ULL * FD * 4);
    float* dinv = (float*)alloc(65536ULL * 4);
    float* scraw= (float*)alloc(65536ULL * 4);
    int*   nid1 = (int*)alloc(65536ULL * 4);
    int*   roff = (int*)alloc((size_t)NB * 513 * 4);
    float2* cpair = (float2*)alloc((size_t)NE * 8);
    float* r1   = (float*)alloc(128ULL * 256 * 4);
    float* r2   = (float*)alloc(128ULL * 256 * 4);

    // ---- stage 1 (512 -> 256): 16 tiles/graph S=4; +128 build-CSR blocks ----
    gemm32<<<2048 + NB, 256, 0, stream>>>(x, W1, hpre, 4, 2048,
                                          src0, dst0, dinv, roff, cpair);
    agg_csr<<<65536 / 4, 256, 0, stream>>>(hpre, roff, cpair, dinv, b1, p1, 9, hbuf, scraw);
    pool_fused<1><<<NB, 1024, 0, stream>>>(hbuf, scraw, p1, xp2, nid1, r1,
                                           src0, dst0, dinv, roff, cpair,
                                           nullptr, nullptr, nullptr, nullptr,
                                           nullptr, nullptr, nullptr, nullptr, nullptr);

    // ---- stage 2 (256 -> 128): 8 tiles/graph S=3 ----
    gemm32<<<1024, 256, 0, stream>>>(xp2, W2, hpre, 3, 1024,
                                     src0, dst0, dinv, roff, cpair);
    agg_csr<<<32768 / 4, 256, 0, stream>>>(hpre, roff, cpair, dinv, b2, p2, 8, hbuf, scraw);
    pool_fused<2><<<NB, 1024, 0, stream>>>(hbuf, scraw, p2, xp3, nid1, r2,
                                           src0, dst0, dinv, roff, cpair,
                                           nullptr, nullptr, nullptr, nullptr,
                                           nullptr, nullptr, nullptr, nullptr, nullptr);

    // ---- stage 3 (128 -> 64): 4 tiles/graph S=2; pool fuses readout+MLP ----
    gemm32<<<512, 256, 0, stream>>>(xp3, W3, hpre, 2, 512,
                                    src0, dst0, dinv, roff, cpair);
    agg_csr<<<16384 / 4, 256, 0, stream>>>(hpre, roff, cpair, dinv, b3, p3, 7, hbuf, scraw);
    pool_fused<3><<<NB, 1024, 0, stream>>>(hbuf, scraw, p3, nullptr, nid1, nullptr,
                                           src0, dst0, dinv, roff, cpair,
                                           r1, r2, L1, bl1, L2, bl2, L3, bl3, out);
}